// Round 10
// baseline (377.964 us; speedup 1.0000x reference)
//
#include <hip/hip_runtime.h>
#include <hip/hip_bf16.h>

#define NPTS 4096
#define BATCH 4
#define BN (BATCH * NPTS)
#define DMODEL 128
#define DPTS 64
#define KNBR 16
#define SWS 136   // padded LDS row stride in bf16 elements
#define PBLK 8    // points per fused block

typedef unsigned short u16;
typedef unsigned int u32;
typedef unsigned long long u64;
typedef short bh8 __attribute__((ext_vector_type(8)));
typedef float f32x4 __attribute__((ext_vector_type(4)));

__device__ __forceinline__ float bfu(u16 u) {
    union { u32 i; float f; } c; c.i = ((u32)u) << 16; return c.f;
}
__device__ __forceinline__ u16 f2u(float x) {   // f32->bf16 RNE
    u32 u = __float_as_uint(x);
    u32 r = u + 0x7FFFu + ((u >> 16) & 1u);
    return (u16)(r >> 16);
}
__device__ __forceinline__ u32 pack2(float a, float b) {
    return (u32)f2u(a) | ((u32)f2u(b) << 16);
}
// mode 0: inputs bf16; mode 1: inputs f32. Runtime-uniform, staging paths only.
__device__ __forceinline__ float ldr(const void* p, long i, int mode) {
    return mode == 0 ? bfu(((const u16*)p)[i]) : ((const float*)p)[i];
}
__device__ __forceinline__ void str(void* p, long i, float v, int mode) {
    if (mode == 0) ((u16*)p)[i] = f2u(v);
    else ((float*)p)[i] = v;
}
// Inline dtype detect: bf16 data has ~0 wild exponent fields; f32-as-u16 has ~84%.
__device__ __forceinline__ int detect_mode(const void* Wq) {
    const u16* w = (const u16*)Wq;
    int lane = threadIdx.x & 63;
    int tot = 0;
#pragma unroll
    for (int r = 0; r < 4; ++r) {
        unsigned e = (w[lane + r * 64] >> 7) & 0xFFu;
        bool wild = (e >= 132u) || (e > 0u && e <= 90u);
        tot += (int)__popcll(__ballot(wild));
    }
    return tot > 32 ? 1 : 0;
}

// ---------------- prep: weight transposes into MFMA B-layouts + f32 cloud ----------
// cloudF[i] = (x, y, z, x^2+y^2+z^2): knn hot loop needs only 3 fma per candidate.
__global__ __launch_bounds__(256) void prep_kernel(
    const void* __restrict__ Wd2, const void* __restrict__ Wg1, const void* __restrict__ Wg2,
    const void* __restrict__ Wo, const void* __restrict__ Wq, const void* __restrict__ Wk,
    const void* __restrict__ Wv, const void* __restrict__ Wf1, const void* __restrict__ xyz,
    u16* __restrict__ WdT2, u16* __restrict__ WgT1, u16* __restrict__ WgT2,
    u16* __restrict__ WoT, u16* __restrict__ WqT, u16* __restrict__ WkT,
    u16* __restrict__ WvT, u16* __restrict__ WfT, float4* __restrict__ cloudF) {
    int mode = detect_mode(Wq);
    int gid = blockIdx.x * 256 + threadIdx.x;
    if (gid < 6 * 16384) {
        int m = gid >> 14, o = gid & 16383;
        int n = o >> 7, i = o & 127;
        const void* W = (m == 0) ? Wd2 : (m == 1) ? Wg1 : (m == 2) ? Wg2
                      : (m == 3) ? Wq  : (m == 4) ? Wk  : Wv;
        u16* D = (m == 0) ? WdT2 : (m == 1) ? WgT1 : (m == 2) ? WgT2
               : (m == 3) ? WqT  : (m == 4) ? WkT  : WvT;
        D[o] = f2u(ldr(W, (long)i * 128 + n, mode));           // W^T[n][i]
    } else if (gid < 6 * 16384 + 8192) {
        int o = gid - 6 * 16384;
        int n = o >> 6, k2 = o & 63;
        WfT[o] = f2u(ldr(Wf1, (long)k2 * 128 + n, mode));      // Wf1^T[n][k]
    } else if (gid < 6 * 16384 + 16384) {
        int o2 = gid - 6 * 16384 - 8192;
        int col = o2 >> 7, i = o2 & 127;
        WoT[o2] = f2u(ldr(Wo, (long)i * 64 + col, mode));      // Wo^T[col][i]
    } else if (gid < 6 * 16384 + 16384 + 16384) {
        int i = gid - (6 * 16384 + 16384);                     // point id 0..BN-1
        float gx = ldr(xyz, (long)i * 3 + 0, mode);
        float gy = ldr(xyz, (long)i * 3 + 1, mode);
        float gz = ldr(xyz, (long)i * 3 + 2, mode);
        float4 f;
        f.x = gx; f.y = gy; f.z = gz;
        f.w = gx * gx + gy * gy + gz * gz;
        cloudF[i] = f;
    }
}

// ---------------- qkv: MFMA, 64 points/block, 4 waves, B from global ----------------
// grid (BN/64, 3): blockIdx.y picks q/k/v; the small f-GEMM is recomputed per block
// (K=64, ~1/7 of block work) to triple the latency-hiding wave count.
__global__ __launch_bounds__(256) void qkv_kernel(
    const void* __restrict__ feat, const void* __restrict__ bf1v, const void* __restrict__ WqRaw,
    const u16* __restrict__ WfT, const u16* __restrict__ WqT,
    const u16* __restrict__ WkT, const u16* __restrict__ WvT,
    u16* __restrict__ qw, u16* __restrict__ kfw, u16* __restrict__ vfw) {
    int mode = detect_mode(WqRaw);
    __shared__ __align__(16) u16 sFeat[64 * 72];
    __shared__ __align__(16) u16 sF[64 * SWS];
    const int t = threadIdx.x;
    const int p0 = blockIdx.x * 64;
    const int lane = t & 63, w = t >> 6;
    const int rg = (w & 1) * 32, cg = (w >> 1) * 64;
    const int lm = lane & 15, lq = lane >> 4;

    for (int i = t; i < 512; i += 256) {       // stage feat tile [64x64]
        int r = i >> 3, c8 = i & 7;
        u16 tmp[8];
        if (mode == 0) {
            *(uint4*)tmp = *((const uint4*)feat + (long)(p0 + r) * 8 + c8);
        } else {
            const float* fp = (const float*)feat + (long)(p0 + r) * 64 + c8 * 8;
#pragma unroll
            for (int u = 0; u < 8; ++u) tmp[u] = f2u(fp[u]);
        }
        *(uint4*)(sFeat + r * 72 + c8 * 8) = *(uint4*)tmp;
    }
    __syncthreads();

    // GEMM1: f = feat @ Wf1 + bf1 -> sF   (B from global WfT, stride 64)
    {
        f32x4 acc[2][4];
#pragma unroll
        for (int rt = 0; rt < 2; ++rt)
#pragma unroll
            for (int ct = 0; ct < 4; ++ct) { acc[rt][ct][0]=0.f; acc[rt][ct][1]=0.f; acc[rt][ct][2]=0.f; acc[rt][ct][3]=0.f; }
#pragma unroll
        for (int kk = 0; kk < 2; ++kk) {
            const int ko = kk * 32 + lq * 8;
            bh8 a0 = *(const bh8*)(sFeat + (rg + lm) * 72 + ko);
            bh8 a1 = *(const bh8*)(sFeat + (rg + 16 + lm) * 72 + ko);
            bh8 bq[4];
#pragma unroll
            for (int ct = 0; ct < 4; ++ct)
                bq[ct] = *(const bh8*)(WfT + (long)(cg + ct * 16 + lm) * 64 + ko);
#pragma unroll
            for (int ct = 0; ct < 4; ++ct) {
                acc[0][ct] = __builtin_amdgcn_mfma_f32_16x16x32_bf16(a0, bq[ct], acc[0][ct], 0, 0, 0);
                acc[1][ct] = __builtin_amdgcn_mfma_f32_16x16x32_bf16(a1, bq[ct], acc[1][ct], 0, 0, 0);
            }
        }
#pragma unroll
        for (int rt = 0; rt < 2; ++rt)
#pragma unroll
            for (int ct = 0; ct < 4; ++ct) {
                const int col = cg + ct * 16 + lm;
                const float bj = ldr(bf1v, col, mode);
#pragma unroll
                for (int r4 = 0; r4 < 4; ++r4) {
                    int row = rg + rt * 16 + lq * 4 + r4;
                    u32 u = (u32)f2u(acc[rt][ct][r4] + bj);
                    u32 o = __shfl_xor(u, 1);
                    if ((lane & 1) == 0)
                        *(u32*)(sF + row * SWS + col) = u | (o << 16);
                }
            }
    }
    __syncthreads();

    // GEMM for this block's m: q/k/v = f @ W   (B from global, stride 128)
    {
        const int m = blockIdx.y;
        const u16* Wm = (m == 0) ? WqT : (m == 1) ? WkT : WvT;
        u16* Om = (m == 0) ? qw : (m == 1) ? kfw : vfw;
        f32x4 acc[2][4];
#pragma unroll
        for (int rt = 0; rt < 2; ++rt)
#pragma unroll
            for (int ct = 0; ct < 4; ++ct) { acc[rt][ct][0]=0.f; acc[rt][ct][1]=0.f; acc[rt][ct][2]=0.f; acc[rt][ct][3]=0.f; }
#pragma unroll
        for (int kk = 0; kk < 4; ++kk) {
            const int ko = kk * 32 + lq * 8;
            bh8 a0 = *(const bh8*)(sF + (rg + lm) * SWS + ko);
            bh8 a1 = *(const bh8*)(sF + (rg + 16 + lm) * SWS + ko);
            bh8 bq[4];
#pragma unroll
            for (int ct = 0; ct < 4; ++ct)
                bq[ct] = *(const bh8*)(Wm + (long)(cg + ct * 16 + lm) * 128 + ko);
#pragma unroll
            for (int ct = 0; ct < 4; ++ct) {
                acc[0][ct] = __builtin_amdgcn_mfma_f32_16x16x32_bf16(a0, bq[ct], acc[0][ct], 0, 0, 0);
                acc[1][ct] = __builtin_amdgcn_mfma_f32_16x16x32_bf16(a1, bq[ct], acc[1][ct], 0, 0, 0);
            }
        }
#pragma unroll
        for (int rt = 0; rt < 2; ++rt)
#pragma unroll
            for (int ct = 0; ct < 4; ++ct) {
                const int col = cg + ct * 16 + lm;
#pragma unroll
                for (int r4 = 0; r4 < 4; ++r4) {
                    int row = rg + rt * 16 + lq * 4 + r4;
                    u32 u = (u32)f2u(acc[rt][ct][r4]);
                    u32 o = __shfl_xor(u, 1);
                    if ((lane & 1) == 0)
                        *(u32*)(Om + (long)(p0 + row) * DMODEL + col) = u | (o << 16);
                }
            }
    }
}

// ---------------- knn: 4-way split scan, 1 point/block, 4 waves --------------------
// Each wave scans 1024 candidates with its own top-16 (insert chain E[44] vs E[66]
// for the full scan, and the 4 chains run in parallel); merge = one 64-lane bitonic
// sort of the 4x16 finalists. Same u64 (dist|idx) keys -> identical selection.
__global__ __launch_bounds__(256) void knn_kernel(
    const float4* __restrict__ cloudF, int* __restrict__ knnIdx) {
    __shared__ u64 sM[64];
    const int t = threadIdx.x, lane = t & 63, w = t >> 6;
    const int pp = blockIdx.x;
    const long bbase = (long)(pp >> 12) * NPTS;
    const float4* cl = cloudF + bbase;

    const int pl = pp & (NPTS - 1);
    float4 qv = cl[pl];
    const float m2x = -2.f * qv.x, m2y = -2.f * qv.y, m2z = -2.f * qv.z;
    const int base0 = w * 1024;

    // seed: candidates [base0, base0+64), 64-lane bitonic sort ascending (u64 key|idx)
    u64 kv;
    {
        float4 c = cl[base0 + lane];
        float key = fmaf(m2x, c.x, fmaf(m2y, c.y, fmaf(m2z, c.z, c.w)));
        u32 uk = __float_as_uint(key);
        uk ^= (u32)((int)uk >> 31) | 0x80000000u;    // monotone float->u32
        kv = ((u64)uk << 32) | (u32)(base0 + lane);
#pragma unroll
        for (int k = 2; k <= 64; k <<= 1) {
#pragma unroll
            for (int j = k >> 1; j > 0; j >>= 1) {
                u64 other = __shfl_xor(kv, j);
                bool keepMin = ((lane & j) == 0) == ((lane & k) == 0);
                bool smaller = kv < other;
                kv = (keepMin == smaller) ? kv : other;
            }
        }
    }
    u32 Tu = __builtin_amdgcn_readlane((u32)(kv >> 32), 15);

    // main loop: candidates [base0+64, base0+1024), 2 candidates/lane/ballot
    float4 cd0 = cl[base0 + 64 + lane];
    float4 cd1 = cl[base0 + 128 + lane];
#pragma unroll 1
    for (int it = 0; it < 8; ++it) {
        const int base = base0 + 64 + it * 128;
        float4 c0 = cd0, c1 = cd1;
        if (it < 7) {
            int n0 = base + 128 + lane;
            int n1 = n0 + 64 > base0 + 1023 ? base0 + 1023 : n0 + 64;
            cd0 = cl[n0];
            cd1 = cl[n1];
        }
        float k0 = fmaf(m2x, c0.x, fmaf(m2y, c0.y, fmaf(m2z, c0.z, c0.w)));
        float k1 = fmaf(m2x, c1.x, fmaf(m2y, c1.y, fmaf(m2z, c1.z, c1.w)));
        u32 u0 = __float_as_uint(k0); u0 ^= (u32)((int)u0 >> 31) | 0x80000000u;
        u32 u1 = __float_as_uint(k1); u1 ^= (u32)((int)u1 >> 31) | 0x80000000u;
        if (it == 7) u1 = 0xFFFFFFFFu;               // c1 range is out of this quarter
        u32 umin = (u0 < u1) ? u0 : u1;
        unsigned long long mask = __ballot(umin < Tu);
        while (mask) {
            int l = __ffsll(mask) - 1;
            mask &= mask - 1;
            u32 a0 = __builtin_amdgcn_readlane(u0, l);
            u32 a1 = __builtin_amdgcn_readlane(u1, l);
            if (a0 < Tu) {
                u64 cand = ((u64)a0 << 32) | (u32)(base + l);
                u64 prev = __shfl_up(kv, 1);
                if (lane == 0) prev = 0;
                kv = (prev > cand) ? prev : ((kv > cand) ? cand : kv);
                Tu = __builtin_amdgcn_readlane((u32)(kv >> 32), 15);
            }
            if (a1 < Tu) {
                u64 cand = ((u64)a1 << 32) | (u32)(base + 64 + l);
                u64 prev = __shfl_up(kv, 1);
                if (lane == 0) prev = 0;
                kv = (prev > cand) ? prev : ((kv > cand) ? cand : kv);
                Tu = __builtin_amdgcn_readlane((u32)(kv >> 32), 15);
            }
        }
    }
    if (lane < 16) sM[w * 16 + lane] = kv;           // each wave's sorted top-16
    __syncthreads();

    if (w == 0) {                                    // merge: 64-lane bitonic of 4x16
        u64 mv = sM[lane];
#pragma unroll
        for (int k = 2; k <= 64; k <<= 1) {
#pragma unroll
            for (int j = k >> 1; j > 0; j >>= 1) {
                u64 other = __shfl_xor(mv, j);
                bool keepMin = ((lane & j) == 0) == ((lane & k) == 0);
                bool smaller = mv < other;
                mv = (keepMin == smaller) ? mv : other;
            }
        }
        if (lane < 16) knnIdx[(long)pp * 16 + lane] = (int)(u32)mv;
    }
}

// ---- 8-wave MFMA phase: D[128x128] = sIn @ Bglobal (+bias, opt relu) -> sOut packed
// Wave w: rows (w&3)*32..+31, cols (w>>2)*64..+63. No state lives across barriers.
// inplace=true: barrier between fragment reads and epilogue writes (sIn may == sOut).
__device__ __forceinline__ void mfma8(const u16* sIn, const u16* __restrict__ Bg,
                                      const float* bias, bool dorelu, bool inplace,
                                      u16* sOut, int t) {
    const int lane = t & 63, w = t >> 6;
    const int rg = (w & 3) * 32, cg = (w >> 2) * 64;
    const int lm = lane & 15, lq = lane >> 4;
    f32x4 acc[2][4];
#pragma unroll
    for (int rt = 0; rt < 2; ++rt)
#pragma unroll
        for (int ct = 0; ct < 4; ++ct) { acc[rt][ct][0]=0.f; acc[rt][ct][1]=0.f; acc[rt][ct][2]=0.f; acc[rt][ct][3]=0.f; }
#pragma unroll
    for (int kk = 0; kk < 4; ++kk) {
        const int ko = kk * 32 + lq * 8;
        bh8 a0 = *(const bh8*)(sIn + (rg + lm) * SWS + ko);
        bh8 a1 = *(const bh8*)(sIn + (rg + 16 + lm) * SWS + ko);
        bh8 bq[4];
#pragma unroll
        for (int ct = 0; ct < 4; ++ct)
            bq[ct] = *(const bh8*)(Bg + (long)(cg + ct * 16 + lm) * 128 + ko);
#pragma unroll
        for (int ct = 0; ct < 4; ++ct) {
            acc[0][ct] = __builtin_amdgcn_mfma_f32_16x16x32_bf16(a0, bq[ct], acc[0][ct], 0, 0, 0);
            acc[1][ct] = __builtin_amdgcn_mfma_f32_16x16x32_bf16(a1, bq[ct], acc[1][ct], 0, 0, 0);
        }
    }
    if (inplace) __syncthreads();
#pragma unroll
    for (int rt = 0; rt < 2; ++rt)
#pragma unroll
        for (int ct = 0; ct < 4; ++ct) {
            const int col = cg + ct * 16 + lm;
            const float bj = bias[col];
#pragma unroll
            for (int r4 = 0; r4 < 4; ++r4) {
                int row = rg + rt * 16 + lq * 4 + r4;
                float v = acc[rt][ct][r4] + bj;
                if (dorelu) v = fmaxf(v, 0.f);
                u32 u = (u32)f2u(v);
                u32 o = __shfl_xor(u, 1);
                if ((lane & 1) == 0)
                    *(u32*)(sOut + row * SWS + col) = u | (o << 16);
            }
        }
}

// ---------------- fused att: 8 points/block, 8 waves, ~74KB LDS --------------------
// Round-5 structure (proven 148us, VGPR 52, no spill) with the A-build fused into
// the PE epilogue: PE accumulators sit at exactly the (row,col) positions A needs,
// so the epilogue emits both sPE (bf16, for softmax) and sA = q - kf + pe (f32 pe).
// Cuts one barrier + one serial LDS round-trip phase from the per-block chain.
#define ATT_SA 0
#define ATT_SPE 34816
#define ATT_SREL 69632
#define ATT_SBIAS 71680
#define ATT_SQ 73216
#define SMEM_BYTES 75264

__global__ __launch_bounds__(512, 4) void fused_kernel(
    const float4* __restrict__ cloudF, const int* __restrict__ knnIdx,
    const void* __restrict__ feat,
    const void* __restrict__ Wd1, const void* __restrict__ bd1, const void* __restrict__ bd2,
    const void* __restrict__ bg1, const void* __restrict__ bg2, const void* __restrict__ bo,
    const void* __restrict__ WqRaw,
    const u16* __restrict__ WdT2, const u16* __restrict__ WgT1, const u16* __restrict__ WgT2,
    const u16* __restrict__ WoT,
    const u16* __restrict__ qw, const u16* __restrict__ kfw, const u16* __restrict__ vfw,
    void* __restrict__ out) {
    int mode = detect_mode(WqRaw);
    __shared__ __align__(16) char smem[SMEM_BYTES];
    __shared__ int sIdx[128];
    u16* sA   = (u16*)(smem + ATT_SA);
    u16* sPE  = (u16*)(smem + ATT_SPE);
    float (*sRel)[4] = (float(*)[4])(smem + ATT_SREL);
    float* sBias = (float*)(smem + ATT_SBIAS);
    u16* sQ   = (u16*)(smem + ATT_SQ);

    const int t = threadIdx.x, lane = t & 63, w = t >> 6;
    const int lm = lane & 15, lq = lane >> 4;
    const int p0 = blockIdx.x * PBLK;
    const long bbase = (long)(p0 >> 12) * NPTS;
    const float4* cl = cloudF + bbase;

    // ---- setup: biases, q, indices, rel (from f32 cloud)
    for (int i = t; i < 384; i += 512) {
        const void* b = (i < 128) ? bd2 : (i < 256) ? bg1 : bg2;
        sBias[i] = ldr(b, i & 127, mode);
    }
    ((u32*)sQ)[t] = ((const u32*)(qw + (long)p0 * DMODEL))[t];
    const int ch = 2 * lane;
    const float wd0a = ldr(Wd1, ch, mode),       wd0b = ldr(Wd1, ch + 1, mode);
    const float wd1a = ldr(Wd1, 128 + ch, mode), wd1b = ldr(Wd1, 128 + ch + 1, mode);
    const float wd2a = ldr(Wd1, 256 + ch, mode), wd2b = ldr(Wd1, 256 + ch + 1, mode);
    const float bd1a = ldr(bd1, ch, mode),       bd1b = ldr(bd1, ch + 1, mode);
    if (t < 128) {
        int idx = knnIdx[(long)p0 * 16 + t];
        sIdx[t] = idx;
        int pl2 = (p0 & (NPTS - 1)) + (t >> 4);
        float4 pv = cl[pl2];
        float4 nv = cl[idx];
        sRel[t][0] = pv.x - nv.x;
        sRel[t][1] = pv.y - nv.y;
        sRel[t][2] = pv.z - nv.z;
    }
    __syncthreads();                              // B1: sRel/sIdx/sQ/sBias ready

    // H1 = relu(rel@Wd1+bd1) -> sA (wave w: rows w*16..+15, channel pair ch)
#pragma unroll
    for (int i = 0; i < 16; ++i) {
        int r = w * 16 + i;
        float4 rl = *(const float4*)sRel[r];
        float h0 = fmaxf(bd1a + rl.x * wd0a + rl.y * wd1a + rl.z * wd2a, 0.f);
        float h1 = fmaxf(bd1b + rl.x * wd0b + rl.y * wd1b + rl.z * wd2b, 0.f);
        *(u32*)(sA + r * SWS + ch) = pack2(h0, h1);
    }
    __syncthreads();                              // B2: H1 in sA

    // PE = H1@Wd2+bd2 (frags from sA); fused epilogue writes sPE AND sA = q - kf + pe
    {
        const int rg = (w & 3) * 32, cg = (w >> 2) * 64;
        f32x4 acc[2][4];
#pragma unroll
        for (int rt = 0; rt < 2; ++rt)
#pragma unroll
            for (int ct = 0; ct < 4; ++ct) { acc[rt][ct][0]=0.f; acc[rt][ct][1]=0.f; acc[rt][ct][2]=0.f; acc[rt][ct][3]=0.f; }
#pragma unroll
        for (int kk = 0; kk < 4; ++kk) {
            const int ko = kk * 32 + lq * 8;
            bh8 a0 = *(const bh8*)(sA + (rg + lm) * SWS + ko);
            bh8 a1 = *(const bh8*)(sA + (rg + 16 + lm) * SWS + ko);
            bh8 bq[4];
#pragma unroll
            for (int ct = 0; ct < 4; ++ct)
                bq[ct] = *(const bh8*)(WdT2 + (long)(cg + ct * 16 + lm) * 128 + ko);
#pragma unroll
            for (int ct = 0; ct < 4; ++ct) {
                acc[0][ct] = __builtin_amdgcn_mfma_f32_16x16x32_bf16(a0, bq[ct], acc[0][ct], 0, 0, 0);
                acc[1][ct] = __builtin_amdgcn_mfma_f32_16x16x32_bf16(a1, bq[ct], acc[1][ct], 0, 0, 0);
            }
        }
        __syncthreads();                          // in-place fence: H1 reads done
#pragma unroll
        for (int rt = 0; rt < 2; ++rt)
#pragma unroll
            for (int ct = 0; ct < 4; ++ct) {
                const int col = cg + ct * 16 + lm;
                const float bj = sBias[col];
                const int pt = (w & 3) * 2 + rt;
                const float qvf = bfu(sQ[pt * DMODEL + col]);
#pragma unroll
                for (int r4 = 0; r4 < 4; ++r4) {
                    int row = rg + rt * 16 + lq * 4 + r4;
                    float pev = acc[rt][ct][r4] + bj;
                    float av = qvf - bfu(kfw[(bbase + sIdx[row]) * (long)DMODEL + col]) + pev;
                    u32 up = (u32)f2u(pev); u32 op = __shfl_xor(up, 1);
                    u32 ua = (u32)f2u(av);  u32 oa = __shfl_xor(ua, 1);
                    if ((lane & 1) == 0) {
                        *(u32*)(sPE + row * SWS + col) = up | (op << 16);
                        *(u32*)(sA  + row * SWS + col) = ua | (oa << 16);
                    }
                }
            }
    }
    __syncthreads();                              // B3: sPE + sA(A) ready
    mfma8(sA, WgT1, sBias + 128, true, true, sA, t);   // G = relu(A@Wg1+bg1), in place
    __syncthreads();                              // B4
    mfma8(sA, WgT2, sBias + 256, false, true, sA, t);  // logits = G@Wg2+bg2, in place
    __syncthreads();                              // B5: logits in sA; sPE intact

    // two-pass softmax over k (wave w = point w); vpe = vfw + pe recomputed here
    float res0, res1;
    {
        float mx0 = -3e38f, mx1 = -3e38f;
#pragma unroll
        for (int k = 0; k < KNBR; ++k) {
            u32 l2 = *(const u32*)(sA + (w * 16 + k) * SWS + ch);
            mx0 = fmaxf(mx0, bfu((u16)l2));
            mx1 = fmaxf(mx1, bfu((u16)(l2 >> 16)));
        }
        const float inv = 0.08838834764831845f;   // 1/sqrt(128)
        float s0 = 0.f, s1 = 0.f, r0 = 0.f, r1 = 0.f;
#pragma unroll
        for (int k = 0; k < KNBR; ++k) {
            u32 l2 = *(const u32*)(sA + (w * 16 + k) * SWS + ch);
            u32 v2 = *(const u32*)(vfw + (bbase + sIdx[w * 16 + k]) * (long)DMODEL + ch);
            u32 p2 = *(const u32*)(sPE + (w * 16 + k) * SWS + ch);
            float e0 = __expf((bfu((u16)l2) - mx0) * inv);
            float e1 = __expf((bfu((u16)(l2 >> 16)) - mx1) * inv);
            s0 += e0; s1 += e1;
            r0 += e0 * (bfu((u16)v2) + bfu((u16)p2));
            r1 += e1 * (bfu((u16)(v2 >> 16)) + bfu((u16)(p2 >> 16)));
        }
        res0 = r0 / s0; res1 = r1 / s1;
    }
    __syncthreads();                              // B6: logits reads done
    *(u32*)(sA + w * SWS + ch) = pack2(res0, res1);   // res -> sA rows 0..7
    __syncthreads();                              // B7

    // out[8x64] = res @ Wo + bo + shortcut (A rows 8..15 garbage -> C rows 8..15
    // garbage, discarded: C row r depends only on A row r)
    if (w < 4) {
        const int col = w * 16 + lm;
        f32x4 acc = {0.f, 0.f, 0.f, 0.f};
#pragma unroll
        for (int kk = 0; kk < 4; ++kk) {
            const int ko = kk * 32 + lq * 8;
            bh8 aa = *(const bh8*)(sA + lm * SWS + ko);
            bh8 bb = *(const bh8*)(WoT + (long)col * DMODEL + ko);
            acc = __builtin_amdgcn_mfma_f32_16x16x32_bf16(aa, bb, acc, 0, 0, 0);
        }
        if (lq < 2) {
            float bov = ldr(bo, col, mode);
#pragma unroll
            for (int r4 = 0; r4 < 4; ++r4) {
                long p = p0 + lq * 4 + r4;
                float v = acc[r4] + bov + ldr(feat, p * DPTS + col, mode);
                str(out, p * DPTS + col, v, mode);
            }
        }
    }
}

extern "C" void kernel_launch(void* const* d_in, const int* in_sizes, int n_in,
                              void* d_out, int out_size, void* d_ws, size_t ws_size,
                              hipStream_t stream) {
    (void)in_sizes; (void)n_in; (void)out_size; (void)ws_size;
    char* ws = (char*)d_ws;
    u16* qw   = (u16*)(ws + 256);
    u16* kfw  = qw + (long)BN * DMODEL;
    u16* vfw  = kfw + (long)BN * DMODEL;
    u16* WdT2 = vfw + (long)BN * DMODEL;
    u16* WgT1 = WdT2 + 16384;
    u16* WgT2 = WgT1 + 16384;
    u16* WoT  = WgT2 + 16384;
    u16* WqT  = WoT + 8192;
    u16* WkT  = WqT + 16384;
    u16* WvT  = WkT + 16384;
    u16* WfT  = WvT + 16384;
    float4* cloudF = (float4*)(WfT + 8192);   // BN float4 = 256KB (16B-aligned)
    int* knnIdx = (int*)(cloudF + BN);        // BN*16 int = 1MB; total ws ~14.2 MB

    prep_kernel<<<512, 256, 0, stream>>>(d_in[4], d_in[11], d_in[13], d_in[15],
                                         d_in[8], d_in[9], d_in[10], d_in[6], d_in[0],
                                         WdT2, WgT1, WgT2, WoT, WqT, WkT, WvT, WfT,
                                         cloudF);
    qkv_kernel<<<dim3(BN / 64, 3), 256, 0, stream>>>(d_in[1], d_in[7], d_in[8],
                                                     WfT, WqT, WkT, WvT, qw, kfw, vfw);
    knn_kernel<<<BN, 256, 0, stream>>>(cloudF, knnIdx);
    fused_kernel<<<BN / PBLK, 512, 0, stream>>>(cloudF, knnIdx, d_in[1],
                                                d_in[2], d_in[3], d_in[5],
                                                d_in[12], d_in[14], d_in[16], d_in[8],
                                                WdT2, WgT1, WgT2, WoT,
                                                qw, kfw, vfw, d_out);
}

// Round 11
// 295.762 us; speedup vs baseline: 1.2779x; 1.2779x over previous
//
#include <hip/hip_runtime.h>
#include <hip/hip_bf16.h>

#define NPTS 4096
#define BATCH 4
#define BN (BATCH * NPTS)
#define DMODEL 128
#define DPTS 64
#define KNBR 16
#define SWS 136   // padded LDS row stride in bf16 elements
#define PBLK 8    // points per fused block

typedef unsigned short u16;
typedef unsigned int u32;
typedef unsigned long long u64;
typedef short bh8 __attribute__((ext_vector_type(8)));
typedef float f32x4 __attribute__((ext_vector_type(4)));

__device__ __forceinline__ float bfu(u16 u) {
    union { u32 i; float f; } c; c.i = ((u32)u) << 16; return c.f;
}
__device__ __forceinline__ u16 f2u(float x) {   // f32->bf16 RNE
    u32 u = __float_as_uint(x);
    u32 r = u + 0x7FFFu + ((u >> 16) & 1u);
    return (u16)(r >> 16);
}
__device__ __forceinline__ u32 pack2(float a, float b) {
    return (u32)f2u(a) | ((u32)f2u(b) << 16);
}
// lane^1 exchange via DPP quad_perm[1,0,3,2] -- VALU, replaces the DS-pipe
// __shfl_xor(u,1) in every epilogue pack (chain-latency + DS-pressure cut).
__device__ __forceinline__ u32 dpp_xor1(u32 v) {
    return (u32)__builtin_amdgcn_update_dpp(0, (int)v, 0xB1, 0xF, 0xF, true);
}
// shfl_up(1) via DPP row_shr:1 (valid within each 16-lane row; knn's insertion
// list only needs lanes 0..15 correct). old=0 -> lane 0 gets prev=0 for free.
__device__ __forceinline__ u32 dpp_shr1(u32 v) {
    return (u32)__builtin_amdgcn_update_dpp(0, (int)v, 0x111, 0xF, 0xF, false);
}
// mode 0: inputs bf16; mode 1: inputs f32. Runtime-uniform, staging paths only.
__device__ __forceinline__ float ldr(const void* p, long i, int mode) {
    return mode == 0 ? bfu(((const u16*)p)[i]) : ((const float*)p)[i];
}
__device__ __forceinline__ void str(void* p, long i, float v, int mode) {
    if (mode == 0) ((u16*)p)[i] = f2u(v);
    else ((float*)p)[i] = v;
}
// Inline dtype detect: bf16 data has ~0 wild exponent fields; f32-as-u16 has ~84%.
__device__ __forceinline__ int detect_mode(const void* Wq) {
    const u16* w = (const u16*)Wq;
    int lane = threadIdx.x & 63;
    int tot = 0;
#pragma unroll
    for (int r = 0; r < 4; ++r) {
        unsigned e = (w[lane + r * 64] >> 7) & 0xFFu;
        bool wild = (e >= 132u) || (e > 0u && e <= 90u);
        tot += (int)__popcll(__ballot(wild));
    }
    return tot > 32 ? 1 : 0;
}

// ---------------- prep: weight transposes into MFMA B-layouts + f32 cloud ----------
// cloudF[i] = (x, y, z, x^2+y^2+z^2): knn hot loop needs only 3 fma per candidate.
__global__ __launch_bounds__(256) void prep_kernel(
    const void* __restrict__ Wd2, const void* __restrict__ Wg1, const void* __restrict__ Wg2,
    const void* __restrict__ Wo, const void* __restrict__ Wq, const void* __restrict__ Wk,
    const void* __restrict__ Wv, const void* __restrict__ Wf1, const void* __restrict__ xyz,
    u16* __restrict__ WdT2, u16* __restrict__ WgT1, u16* __restrict__ WgT2,
    u16* __restrict__ WoT, u16* __restrict__ WqT, u16* __restrict__ WkT,
    u16* __restrict__ WvT, u16* __restrict__ WfT, float4* __restrict__ cloudF) {
    int mode = detect_mode(Wq);
    int gid = blockIdx.x * 256 + threadIdx.x;
    if (gid < 6 * 16384) {
        int m = gid >> 14, o = gid & 16383;
        int n = o >> 7, i = o & 127;
        const void* W = (m == 0) ? Wd2 : (m == 1) ? Wg1 : (m == 2) ? Wg2
                      : (m == 3) ? Wq  : (m == 4) ? Wk  : Wv;
        u16* D = (m == 0) ? WdT2 : (m == 1) ? WgT1 : (m == 2) ? WgT2
               : (m == 3) ? WqT  : (m == 4) ? WkT  : WvT;
        D[o] = f2u(ldr(W, (long)i * 128 + n, mode));           // W^T[n][i]
    } else if (gid < 6 * 16384 + 8192) {
        int o = gid - 6 * 16384;
        int n = o >> 6, k2 = o & 63;
        WfT[o] = f2u(ldr(Wf1, (long)k2 * 128 + n, mode));      // Wf1^T[n][k]
    } else if (gid < 6 * 16384 + 16384) {
        int o2 = gid - 6 * 16384 - 8192;
        int col = o2 >> 7, i = o2 & 127;
        WoT[o2] = f2u(ldr(Wo, (long)i * 64 + col, mode));      // Wo^T[col][i]
    } else if (gid < 6 * 16384 + 16384 + 16384) {
        int i = gid - (6 * 16384 + 16384);                     // point id 0..BN-1
        float gx = ldr(xyz, (long)i * 3 + 0, mode);
        float gy = ldr(xyz, (long)i * 3 + 1, mode);
        float gz = ldr(xyz, (long)i * 3 + 2, mode);
        float4 f;
        f.x = gx; f.y = gy; f.z = gz;
        f.w = gx * gx + gy * gy + gz * gz;
        cloudF[i] = f;
    }
}

// ---------------- qkv: MFMA, 64 points/block, 4 waves, B from global ----------------
// grid (BN/64, 3): blockIdx.y picks q/k/v; the small f-GEMM is recomputed per block
// (K=64, ~1/7 of block work) to triple the latency-hiding wave count.
__global__ __launch_bounds__(256) void qkv_kernel(
    const void* __restrict__ feat, const void* __restrict__ bf1v, const void* __restrict__ WqRaw,
    const u16* __restrict__ WfT, const u16* __restrict__ WqT,
    const u16* __restrict__ WkT, const u16* __restrict__ WvT,
    u16* __restrict__ qw, u16* __restrict__ kfw, u16* __restrict__ vfw) {
    int mode = detect_mode(WqRaw);
    __shared__ __align__(16) u16 sFeat[64 * 72];
    __shared__ __align__(16) u16 sF[64 * SWS];
    const int t = threadIdx.x;
    const int p0 = blockIdx.x * 64;
    const int lane = t & 63, w = t >> 6;
    const int rg = (w & 1) * 32, cg = (w >> 1) * 64;
    const int lm = lane & 15, lq = lane >> 4;

    for (int i = t; i < 512; i += 256) {       // stage feat tile [64x64]
        int r = i >> 3, c8 = i & 7;
        u16 tmp[8];
        if (mode == 0) {
            *(uint4*)tmp = *((const uint4*)feat + (long)(p0 + r) * 8 + c8);
        } else {
            const float* fp = (const float*)feat + (long)(p0 + r) * 64 + c8 * 8;
#pragma unroll
            for (int u = 0; u < 8; ++u) tmp[u] = f2u(fp[u]);
        }
        *(uint4*)(sFeat + r * 72 + c8 * 8) = *(uint4*)tmp;
    }
    __syncthreads();

    // GEMM1: f = feat @ Wf1 + bf1 -> sF   (B from global WfT, stride 64)
    {
        f32x4 acc[2][4];
#pragma unroll
        for (int rt = 0; rt < 2; ++rt)
#pragma unroll
            for (int ct = 0; ct < 4; ++ct) { acc[rt][ct][0]=0.f; acc[rt][ct][1]=0.f; acc[rt][ct][2]=0.f; acc[rt][ct][3]=0.f; }
#pragma unroll
        for (int kk = 0; kk < 2; ++kk) {
            const int ko = kk * 32 + lq * 8;
            bh8 a0 = *(const bh8*)(sFeat + (rg + lm) * 72 + ko);
            bh8 a1 = *(const bh8*)(sFeat + (rg + 16 + lm) * 72 + ko);
            bh8 bq[4];
#pragma unroll
            for (int ct = 0; ct < 4; ++ct)
                bq[ct] = *(const bh8*)(WfT + (long)(cg + ct * 16 + lm) * 64 + ko);
#pragma unroll
            for (int ct = 0; ct < 4; ++ct) {
                acc[0][ct] = __builtin_amdgcn_mfma_f32_16x16x32_bf16(a0, bq[ct], acc[0][ct], 0, 0, 0);
                acc[1][ct] = __builtin_amdgcn_mfma_f32_16x16x32_bf16(a1, bq[ct], acc[1][ct], 0, 0, 0);
            }
        }
#pragma unroll
        for (int rt = 0; rt < 2; ++rt)
#pragma unroll
            for (int ct = 0; ct < 4; ++ct) {
                const int col = cg + ct * 16 + lm;
                const float bj = ldr(bf1v, col, mode);
#pragma unroll
                for (int r4 = 0; r4 < 4; ++r4) {
                    int row = rg + rt * 16 + lq * 4 + r4;
                    u32 u = (u32)f2u(acc[rt][ct][r4] + bj);
                    u32 o = dpp_xor1(u);
                    if ((lane & 1) == 0)
                        *(u32*)(sF + row * SWS + col) = u | (o << 16);
                }
            }
    }
    __syncthreads();

    // GEMM for this block's m: q/k/v = f @ W   (B from global, stride 128)
    {
        const int m = blockIdx.y;
        const u16* Wm = (m == 0) ? WqT : (m == 1) ? WkT : WvT;
        u16* Om = (m == 0) ? qw : (m == 1) ? kfw : vfw;
        f32x4 acc[2][4];
#pragma unroll
        for (int rt = 0; rt < 2; ++rt)
#pragma unroll
            for (int ct = 0; ct < 4; ++ct) { acc[rt][ct][0]=0.f; acc[rt][ct][1]=0.f; acc[rt][ct][2]=0.f; acc[rt][ct][3]=0.f; }
#pragma unroll
        for (int kk = 0; kk < 4; ++kk) {
            const int ko = kk * 32 + lq * 8;
            bh8 a0 = *(const bh8*)(sF + (rg + lm) * SWS + ko);
            bh8 a1 = *(const bh8*)(sF + (rg + 16 + lm) * SWS + ko);
            bh8 bq[4];
#pragma unroll
            for (int ct = 0; ct < 4; ++ct)
                bq[ct] = *(const bh8*)(Wm + (long)(cg + ct * 16 + lm) * 128 + ko);
#pragma unroll
            for (int ct = 0; ct < 4; ++ct) {
                acc[0][ct] = __builtin_amdgcn_mfma_f32_16x16x32_bf16(a0, bq[ct], acc[0][ct], 0, 0, 0);
                acc[1][ct] = __builtin_amdgcn_mfma_f32_16x16x32_bf16(a1, bq[ct], acc[1][ct], 0, 0, 0);
            }
        }
#pragma unroll
        for (int rt = 0; rt < 2; ++rt)
#pragma unroll
            for (int ct = 0; ct < 4; ++ct) {
                const int col = cg + ct * 16 + lm;
#pragma unroll
                for (int r4 = 0; r4 < 4; ++r4) {
                    int row = rg + rt * 16 + lq * 4 + r4;
                    u32 u = (u32)f2u(acc[rt][ct][r4]);
                    u32 o = dpp_xor1(u);
                    if ((lane & 1) == 0)
                        *(u32*)(Om + (long)(p0 + row) * DMODEL + col) = u | (o << 16);
                }
            }
    }
}

// ---------------- knn: dedicated scan kernel, zero LDS, 4 points/block -------------
// r5 full-scan structure (r9's 4-way split tripled total insert work: reverted).
// Insert chain's shfl_up(kv,1) -> DPP row_shr:1 (VALU): only lanes 0..15 of the
// insertion list are ever read (top-16 + Tu@lane15), so row-local shift is exact.
__global__ __launch_bounds__(256) void knn_kernel(
    const float4* __restrict__ cloudF, int* __restrict__ knnIdx) {
    const int t = threadIdx.x, lane = t & 63, w = t >> 6;
    const int p0 = blockIdx.x * 4;
    const long bbase = (long)(p0 >> 12) * NPTS;
    const float4* cl = cloudF + bbase;

    const int pl = (p0 & (NPTS - 1)) + w;
    float4 qv = cl[pl];
    const float m2x = -2.f * qv.x, m2y = -2.f * qv.y, m2z = -2.f * qv.z;

    // seed: keys of candidates 0..63, 64-lane bitonic sort ascending (u64 key|idx)
    u64 kv;
    {
        float4 c = cl[lane];
        float key = fmaf(m2x, c.x, fmaf(m2y, c.y, fmaf(m2z, c.z, c.w)));
        u32 uk = __float_as_uint(key);
        uk ^= (u32)((int)uk >> 31) | 0x80000000u;    // monotone float->u32
        kv = ((u64)uk << 32) | (u32)lane;
#pragma unroll
        for (int k = 2; k <= 64; k <<= 1) {
#pragma unroll
            for (int j = k >> 1; j > 0; j >>= 1) {
                u64 other = __shfl_xor(kv, j);
                bool keepMin = ((lane & j) == 0) == ((lane & k) == 0);
                bool smaller = kv < other;
                kv = (keepMin == smaller) ? kv : other;
            }
        }
    }
    u32 Tu = __builtin_amdgcn_readlane((u32)(kv >> 32), 15);

    // main loop: candidates 64..4095, 2 candidates/lane/ballot
    float4 cd0 = cl[64 + lane];
    float4 cd1 = cl[128 + lane];
#pragma unroll 1
    for (int it = 0; it < 32; ++it) {
        const int base = 64 + it * 128;
        float4 c0 = cd0, c1 = cd1;
        if (it < 31) {
            int n0 = base + 128 + lane;
            int n1 = n0 + 64 > 4095 ? 4095 : n0 + 64;
            cd0 = cl[n0];
            cd1 = cl[n1];
        }
        float k0 = fmaf(m2x, c0.x, fmaf(m2y, c0.y, fmaf(m2z, c0.z, c0.w)));
        float k1 = fmaf(m2x, c1.x, fmaf(m2y, c1.y, fmaf(m2z, c1.z, c1.w)));
        u32 u0 = __float_as_uint(k0); u0 ^= (u32)((int)u0 >> 31) | 0x80000000u;
        u32 u1 = __float_as_uint(k1); u1 ^= (u32)((int)u1 >> 31) | 0x80000000u;
        if (it == 31) u1 = 0xFFFFFFFFu;              // c1 range is out of bounds
        u32 umin = (u0 < u1) ? u0 : u1;
        unsigned long long mask = __ballot(umin < Tu);
        while (mask) {
            int l = __ffsll(mask) - 1;
            mask &= mask - 1;
            u32 a0 = __builtin_amdgcn_readlane(u0, l);
            u32 a1 = __builtin_amdgcn_readlane(u1, l);
            if (a0 < Tu) {
                u64 cand = ((u64)a0 << 32) | (u32)(base + l);
                u64 prev = ((u64)dpp_shr1((u32)(kv >> 32)) << 32) | dpp_shr1((u32)kv);
                kv = (prev > cand) ? prev : ((kv > cand) ? cand : kv);
                Tu = __builtin_amdgcn_readlane((u32)(kv >> 32), 15);
            }
            if (a1 < Tu) {
                u64 cand = ((u64)a1 << 32) | (u32)(base + 64 + l);
                u64 prev = ((u64)dpp_shr1((u32)(kv >> 32)) << 32) | dpp_shr1((u32)kv);
                kv = (prev > cand) ? prev : ((kv > cand) ? cand : kv);
                Tu = __builtin_amdgcn_readlane((u32)(kv >> 32), 15);
            }
        }
    }
    if (lane < 16) knnIdx[(long)(p0 + w) * 16 + lane] = (int)(u32)kv;
}

// ---- 8-wave MFMA phase: D[128x128] = sIn @ Bglobal (+bias, opt relu) -> sOut packed
// Wave w: rows (w&3)*32..+31, cols (w>>2)*64..+63. No state lives across barriers.
// inplace=true: barrier between fragment reads and epilogue writes (sIn may == sOut).
__device__ __forceinline__ void mfma8(const u16* sIn, const u16* __restrict__ Bg,
                                      const float* bias, bool dorelu, bool inplace,
                                      u16* sOut, int t) {
    const int lane = t & 63, w = t >> 6;
    const int rg = (w & 3) * 32, cg = (w >> 2) * 64;
    const int lm = lane & 15, lq = lane >> 4;
    f32x4 acc[2][4];
#pragma unroll
    for (int rt = 0; rt < 2; ++rt)
#pragma unroll
        for (int ct = 0; ct < 4; ++ct) { acc[rt][ct][0]=0.f; acc[rt][ct][1]=0.f; acc[rt][ct][2]=0.f; acc[rt][ct][3]=0.f; }
#pragma unroll
    for (int kk = 0; kk < 4; ++kk) {
        const int ko = kk * 32 + lq * 8;
        bh8 a0 = *(const bh8*)(sIn + (rg + lm) * SWS + ko);
        bh8 a1 = *(const bh8*)(sIn + (rg + 16 + lm) * SWS + ko);
        bh8 bq[4];
#pragma unroll
        for (int ct = 0; ct < 4; ++ct)
            bq[ct] = *(const bh8*)(Bg + (long)(cg + ct * 16 + lm) * 128 + ko);
#pragma unroll
        for (int ct = 0; ct < 4; ++ct) {
            acc[0][ct] = __builtin_amdgcn_mfma_f32_16x16x32_bf16(a0, bq[ct], acc[0][ct], 0, 0, 0);
            acc[1][ct] = __builtin_amdgcn_mfma_f32_16x16x32_bf16(a1, bq[ct], acc[1][ct], 0, 0, 0);
        }
    }
    if (inplace) __syncthreads();
#pragma unroll
    for (int rt = 0; rt < 2; ++rt)
#pragma unroll
        for (int ct = 0; ct < 4; ++ct) {
            const int col = cg + ct * 16 + lm;
            const float bj = bias[col];
#pragma unroll
            for (int r4 = 0; r4 < 4; ++r4) {
                int row = rg + rt * 16 + lq * 4 + r4;
                float v = acc[rt][ct][r4] + bj;
                if (dorelu) v = fmaxf(v, 0.f);
                u32 u = (u32)f2u(v);
                u32 o = dpp_xor1(u);
                if ((lane & 1) == 0)
                    *(u32*)(sOut + row * SWS + col) = u | (o << 16);
            }
        }
}

// ---------------- fused att: 8 points/block, 8 waves, ~74KB LDS --------------------
// Round-5 structure (proven 148us, VGPR 52, no spill): separate coalesced A-build
// (r10's epilogue-fused gather was scattered: reverted). Epilogue packs via DPP.
#define ATT_SA 0
#define ATT_SPE 34816
#define ATT_SREL 69632
#define ATT_SBIAS 71680
#define ATT_SQ 73216
#define SMEM_BYTES 75264

__global__ __launch_bounds__(512, 4) void fused_kernel(
    const float4* __restrict__ cloudF, const int* __restrict__ knnIdx,
    const void* __restrict__ feat,
    const void* __restrict__ Wd1, const void* __restrict__ bd1, const void* __restrict__ bd2,
    const void* __restrict__ bg1, const void* __restrict__ bg2, const void* __restrict__ bo,
    const void* __restrict__ WqRaw,
    const u16* __restrict__ WdT2, const u16* __restrict__ WgT1, const u16* __restrict__ WgT2,
    const u16* __restrict__ WoT,
    const u16* __restrict__ qw, const u16* __restrict__ kfw, const u16* __restrict__ vfw,
    void* __restrict__ out) {
    int mode = detect_mode(WqRaw);
    __shared__ __align__(16) char smem[SMEM_BYTES];
    __shared__ int sIdx[128];
    u16* sA   = (u16*)(smem + ATT_SA);
    u16* sPE  = (u16*)(smem + ATT_SPE);
    float (*sRel)[4] = (float(*)[4])(smem + ATT_SREL);
    float* sBias = (float*)(smem + ATT_SBIAS);
    u16* sQ   = (u16*)(smem + ATT_SQ);

    const int t = threadIdx.x, lane = t & 63, w = t >> 6;
    const int lm = lane & 15, lq = lane >> 4;
    const int p0 = blockIdx.x * PBLK;
    const long bbase = (long)(p0 >> 12) * NPTS;
    const float4* cl = cloudF + bbase;

    // ---- setup: biases, q, indices, rel (from f32 cloud)
    for (int i = t; i < 384; i += 512) {
        const void* b = (i < 128) ? bd2 : (i < 256) ? bg1 : bg2;
        sBias[i] = ldr(b, i & 127, mode);
    }
    ((u32*)sQ)[t] = ((const u32*)(qw + (long)p0 * DMODEL))[t];
    const int ch = 2 * lane;
    const float wd0a = ldr(Wd1, ch, mode),       wd0b = ldr(Wd1, ch + 1, mode);
    const float wd1a = ldr(Wd1, 128 + ch, mode), wd1b = ldr(Wd1, 128 + ch + 1, mode);
    const float wd2a = ldr(Wd1, 256 + ch, mode), wd2b = ldr(Wd1, 256 + ch + 1, mode);
    const float bd1a = ldr(bd1, ch, mode),       bd1b = ldr(bd1, ch + 1, mode);
    if (t < 128) {
        int idx = knnIdx[(long)p0 * 16 + t];
        sIdx[t] = idx;
        int pl2 = (p0 & (NPTS - 1)) + (t >> 4);
        float4 pv = cl[pl2];
        float4 nv = cl[idx];
        sRel[t][0] = pv.x - nv.x;
        sRel[t][1] = pv.y - nv.y;
        sRel[t][2] = pv.z - nv.z;
    }
    __syncthreads();                              // B1: sRel/sIdx/sQ/sBias ready

    // H1 = relu(rel@Wd1+bd1) -> sA (wave w: rows w*16..+15, channel pair ch)
#pragma unroll
    for (int i = 0; i < 16; ++i) {
        int r = w * 16 + i;
        float4 rl = *(const float4*)sRel[r];
        float h0 = fmaxf(bd1a + rl.x * wd0a + rl.y * wd1a + rl.z * wd2a, 0.f);
        float h1 = fmaxf(bd1b + rl.x * wd0b + rl.y * wd1b + rl.z * wd2b, 0.f);
        *(u32*)(sA + r * SWS + ch) = pack2(h0, h1);
    }
    __syncthreads();                              // B2: H1 in sA
    mfma8(sA, WdT2, sBias, false, false, sPE, t); // PE = H1@Wd2+bd2 -> sPE
    __syncthreads();                              // B3: sPE ready; PE's sA reads done

    // A = q - kf + pe -> sA (coalesced u32 gathers at channel pair ch)
#pragma unroll
    for (int i = 0; i < 16; ++i) {
        int r = w * 16 + i;
        u32 kv2 = *(const u32*)(kfw + (bbase + sIdx[r]) * (long)DMODEL + ch);
        u32 qv2 = *(const u32*)(sQ + (r >> 4) * DMODEL + ch);
        u32 pe2 = *(const u32*)(sPE + r * SWS + ch);
        float a0 = bfu((u16)qv2) - bfu((u16)kv2) + bfu((u16)pe2);
        float a1 = bfu((u16)(qv2 >> 16)) - bfu((u16)(kv2 >> 16)) + bfu((u16)(pe2 >> 16));
        *(u32*)(sA + r * SWS + ch) = pack2(a0, a1);
    }
    __syncthreads();                              // B4: A in sA
    mfma8(sA, WgT1, sBias + 128, true, true, sA, t);   // G = relu(A@Wg1+bg1), in place
    __syncthreads();                              // B5
    mfma8(sA, WgT2, sBias + 256, false, true, sA, t);  // logits = G@Wg2+bg2, in place
    __syncthreads();                              // B6: logits in sA; sPE intact

    // two-pass softmax over k (wave w = point w); vpe = vfw + pe recomputed here
    float res0, res1;
    {
        float mx0 = -3e38f, mx1 = -3e38f;
#pragma unroll
        for (int k = 0; k < KNBR; ++k) {
            u32 l2 = *(const u32*)(sA + (w * 16 + k) * SWS + ch);
            mx0 = fmaxf(mx0, bfu((u16)l2));
            mx1 = fmaxf(mx1, bfu((u16)(l2 >> 16)));
        }
        const float inv = 0.08838834764831845f;   // 1/sqrt(128)
        float s0 = 0.f, s1 = 0.f, r0 = 0.f, r1 = 0.f;
#pragma unroll
        for (int k = 0; k < KNBR; ++k) {
            u32 l2 = *(const u32*)(sA + (w * 16 + k) * SWS + ch);
            u32 v2 = *(const u32*)(vfw + (bbase + sIdx[w * 16 + k]) * (long)DMODEL + ch);
            u32 p2 = *(const u32*)(sPE + (w * 16 + k) * SWS + ch);
            float e0 = __expf((bfu((u16)l2) - mx0) * inv);
            float e1 = __expf((bfu((u16)(l2 >> 16)) - mx1) * inv);
            s0 += e0; s1 += e1;
            r0 += e0 * (bfu((u16)v2) + bfu((u16)p2));
            r1 += e1 * (bfu((u16)(v2 >> 16)) + bfu((u16)(p2 >> 16)));
        }
        res0 = r0 / s0; res1 = r1 / s1;
    }
    __syncthreads();                              // B7: logits reads done
    *(u32*)(sA + w * SWS + ch) = pack2(res0, res1);   // res -> sA rows 0..7
    __syncthreads();                              // B8

    // out[8x64] = res @ Wo + bo + shortcut (A rows 8..15 garbage -> C rows 8..15
    // garbage, discarded: C row r depends only on A row r)
    if (w < 4) {
        const int col = w * 16 + lm;
        f32x4 acc = {0.f, 0.f, 0.f, 0.f};
#pragma unroll
        for (int kk = 0; kk < 4; ++kk) {
            const int ko = kk * 32 + lq * 8;
            bh8 aa = *(const bh8*)(sA + lm * SWS + ko);
            bh8 bb = *(const bh8*)(WoT + (long)col * DMODEL + ko);
            acc = __builtin_amdgcn_mfma_f32_16x16x32_bf16(aa, bb, acc, 0, 0, 0);
        }
        if (lq < 2) {
            float bov = ldr(bo, col, mode);
#pragma unroll
            for (int r4 = 0; r4 < 4; ++r4) {
                long p = p0 + lq * 4 + r4;
                float v = acc[r4] + bov + ldr(feat, p * DPTS + col, mode);
                str(out, p * DPTS + col, v, mode);
            }
        }
    }
}

extern "C" void kernel_launch(void* const* d_in, const int* in_sizes, int n_in,
                              void* d_out, int out_size, void* d_ws, size_t ws_size,
                              hipStream_t stream) {
    (void)in_sizes; (void)n_in; (void)out_size; (void)ws_size;
    char* ws = (char*)d_ws;
    u16* qw   = (u16*)(ws + 256);
    u16* kfw  = qw + (long)BN * DMODEL;
    u16* vfw  = kfw + (long)BN * DMODEL;
    u16* WdT2 = vfw + (long)BN * DMODEL;
    u16* WgT1 = WdT2 + 16384;
    u16* WgT2 = WgT1 + 16384;
    u16* WoT  = WgT2 + 16384;
    u16* WqT  = WoT + 8192;
    u16* WkT  = WqT + 16384;
    u16* WvT  = WkT + 16384;
    u16* WfT  = WvT + 16384;
    float4* cloudF = (float4*)(WfT + 8192);   // BN float4 = 256KB (16B-aligned)
    int* knnIdx = (int*)(cloudF + BN);        // BN*16 int = 1MB; total ws ~14.2 MB

    prep_kernel<<<512, 256, 0, stream>>>(d_in[4], d_in[11], d_in[13], d_in[15],
                                         d_in[8], d_in[9], d_in[10], d_in[6], d_in[0],
                                         WdT2, WgT1, WgT2, WoT, WqT, WkT, WvT, WfT,
                                         cloudF);
    qkv_kernel<<<dim3(BN / 64, 3), 256, 0, stream>>>(d_in[1], d_in[7], d_in[8],
                                                     WfT, WqT, WkT, WvT, qw, kfw, vfw);
    knn_kernel<<<BN / 4, 256, 0, stream>>>(cloudF, knnIdx);
    fused_kernel<<<BN / PBLK, 512, 0, stream>>>(cloudF, knnIdx, d_in[1],
                                                d_in[2], d_in[3], d_in[5],
                                                d_in[12], d_in[14], d_in[16], d_in[8],
                                                WdT2, WgT1, WgT2, WoT,
                                                qw, kfw, vfw, d_out);
}